// Round 5
// baseline (104.200 us; speedup 1.0000x reference)
//
#include <hip/hip_runtime.h>

// Problem sizes (compile-time)
constexpr int B_ = 16, T_ = 300, U_ = 30;
constexpr int J_ = 512;       // ENC/DEC/JOINER dim
constexpr int V_ = 500;       // VOCAB
constexpr int BT_ = B_ * T_;  // 4800 (divisible by 64)
constexpr int BU_ = B_ * U_;  // 480
constexpr int KD  = 512;      // K of all GEMMs
constexpr int NP  = 512;      // padded N / row stride

typedef __attribute__((ext_vector_type(8))) short short8v;  // 8 bf16
typedef __attribute__((ext_vector_type(4))) float f32x4;    // native 16B vector

__device__ __forceinline__ ushort f2bf(float f) {
    unsigned u = __builtin_bit_cast(unsigned, f);
    u += 0x7FFFu + ((u >> 16) & 1u);
    return (ushort)(u >> 16);
}

// direct global->LDS async copy, 16B per lane (wave-uniform LDS base)
#define GLOAD16(gsrc, ldst)                                                   \
    __builtin_amdgcn_global_load_lds(                                         \
        (const __attribute__((address_space(1))) unsigned int*)(const void*)(gsrc), \
        (__attribute__((address_space(3))) unsigned int*)(void*)(ldst), 16, 0, 0)

// ---------------------------------------------------------------------------
// prep: one launch, role by blockIdx.x range
//  [0,1200)    enc f32 -> encB bf16            (4800x512)
//  [1200,1328) dec f32 -> decB bf16, rows 480..511 zeroed (512x512)
//  [1328,1392) W_enc^T -> WeT bf16             (WeT[d][j] = W_enc[j][d])
//  [1392,1456) W_dec^T -> WdT bf16
//  [1456,1584) W_out -> WoB bf16 (rows 500..511 zero) + be/bd bias dots
// ---------------------------------------------------------------------------
__global__ __launch_bounds__(256) void prep(
    const float* __restrict__ enc, const float* __restrict__ dec,
    const float* __restrict__ W_enc, const float* __restrict__ W_dec,
    const float* __restrict__ W_out, const float* __restrict__ b_enc,
    const float* __restrict__ b_dec, const float* __restrict__ b_out,
    ushort* __restrict__ encB, ushort* __restrict__ decB,
    ushort* __restrict__ WeT, ushort* __restrict__ WdT,
    ushort* __restrict__ WoB, float* __restrict__ be, float* __restrict__ bd)
{
    __shared__ ushort ts[64][65];
    const int bid = blockIdx.x;
    const int tid = threadIdx.x;

    if (bid < 1200) {                       // enc convert: 2048 floats/block
        const size_t idx = (size_t)bid * 2048 + tid * 8;
        float4 f0 = *reinterpret_cast<const float4*>(enc + idx);
        float4 f1 = *reinterpret_cast<const float4*>(enc + idx + 4);
        short8v o; o[0]=(short)f2bf(f0.x); o[1]=(short)f2bf(f0.y);
        o[2]=(short)f2bf(f0.z); o[3]=(short)f2bf(f0.w);
        o[4]=(short)f2bf(f1.x); o[5]=(short)f2bf(f1.y);
        o[6]=(short)f2bf(f1.z); o[7]=(short)f2bf(f1.w);
        *reinterpret_cast<short8v*>(encB + idx) = o;
    } else if (bid < 1328) {                // dec convert + pad
        const size_t idx = (size_t)(bid - 1200) * 2048 + tid * 8;
        const int row = (int)(idx >> 9);
        short8v o = {};
        if (row < BU_) {
            float4 f0 = *reinterpret_cast<const float4*>(dec + idx);
            float4 f1 = *reinterpret_cast<const float4*>(dec + idx + 4);
            o[0]=(short)f2bf(f0.x); o[1]=(short)f2bf(f0.y);
            o[2]=(short)f2bf(f0.z); o[3]=(short)f2bf(f0.w);
            o[4]=(short)f2bf(f1.x); o[5]=(short)f2bf(f1.y);
            o[6]=(short)f2bf(f1.z); o[7]=(short)f2bf(f1.w);
        }
        *reinterpret_cast<short8v*>(decB + idx) = o;
    } else if (bid < 1456) {                // transpose W_enc / W_dec (64x64 tiles)
        const bool isE = bid < 1392;
        const int t = bid - (isE ? 1328 : 1392);   // 0..63
        const float*  W = isE ? W_enc : W_dec;
        ushort*      WT = isE ? WeT : WdT;
        const int r0 = (t >> 3) * 64, c0 = (t & 7) * 64;
        #pragma unroll
        for (int it = 0; it < 4; ++it) {
            const int idx = tid + it * 256;        // 0..1023
            const int r = idx >> 4, c4 = (idx & 15) * 4;
            float4 f = *reinterpret_cast<const float4*>(&W[(size_t)(r0 + r) * 512 + c0 + c4]);
            ts[r][c4 + 0] = f2bf(f.x); ts[r][c4 + 1] = f2bf(f.y);
            ts[r][c4 + 2] = f2bf(f.z); ts[r][c4 + 3] = f2bf(f.w);
        }
        __syncthreads();
        #pragma unroll
        for (int it = 0; it < 4; ++it) {
            const int idx = tid + it * 256;
            const int c = idx >> 4, r4 = (idx & 15) * 4;
            ushort4 o;
            o.x = ts[r4 + 0][c]; o.y = ts[r4 + 1][c];
            o.z = ts[r4 + 2][c]; o.w = ts[r4 + 3][c];
            *reinterpret_cast<ushort4*>(&WT[(size_t)(c0 + c) * 512 + r0 + r4]) = o;
        }
    } else {                                // W_out rows + folded biases
        const int v    = (bid - 1456) * 4 + (tid >> 6);  // 0..511
        const int lane = tid & 63;
        float4 f0 = make_float4(0, 0, 0, 0), f1 = f0;
        if (v < V_) {
            f0 = *reinterpret_cast<const float4*>(&W_out[(size_t)v * 512 + lane * 8]);
            f1 = *reinterpret_cast<const float4*>(&W_out[(size_t)v * 512 + lane * 8 + 4]);
        }
        short8v o; o[0]=(short)f2bf(f0.x); o[1]=(short)f2bf(f0.y);
        o[2]=(short)f2bf(f0.z); o[3]=(short)f2bf(f0.w);
        o[4]=(short)f2bf(f1.x); o[5]=(short)f2bf(f1.y);
        o[6]=(short)f2bf(f1.z); o[7]=(short)f2bf(f1.w);
        *reinterpret_cast<short8v*>(WoB + (size_t)v * 512 + lane * 8) = o;

        float4 e0 = *reinterpret_cast<const float4*>(b_enc + lane * 8);
        float4 e1 = *reinterpret_cast<const float4*>(b_enc + lane * 8 + 4);
        float4 d0 = *reinterpret_cast<const float4*>(b_dec + lane * 8);
        float4 d1 = *reinterpret_cast<const float4*>(b_dec + lane * 8 + 4);
        float sE = f0.x*e0.x + f0.y*e0.y + f0.z*e0.z + f0.w*e0.w
                 + f1.x*e1.x + f1.y*e1.y + f1.z*e1.z + f1.w*e1.w;
        float sD = f0.x*d0.x + f0.y*d0.y + f0.z*d0.z + f0.w*d0.w
                 + f1.x*d1.x + f1.y*d1.y + f1.z*d1.z + f1.w*d1.w;
        #pragma unroll
        for (int off = 32; off > 0; off >>= 1) {
            sE += __shfl_down(sE, off);
            sD += __shfl_down(sD, off);
        }
        if (lane == 0) {
            be[v] = (v < V_) ? sE : 0.0f;
            bd[v] = (v < V_) ? (sD + b_out[v]) : 0.0f;
        }
    }
}

// ---------------------------------------------------------------------------
// bf16 NT GEMM, 64x64 tile, BK=64, double-buffered 2-phase pipeline
// (T3-min recipe: STAGE(next) -> compute(cur) -> one barrier per K-tile).
// C(M x 512) = A(M x 512) @ B(512 x 512)^T [+ bias]; M multiple of 64.
// ---------------------------------------------------------------------------
template <bool OUT_BF16>
__device__ __forceinline__ void gemm_body(
    const ushort* __restrict__ A, const ushort* __restrict__ Bm,
    const float* __restrict__ bias, void* __restrict__ C,
    int m0, int n0)
{
    __shared__ ushort a_s[2][2][64 * 32];   // [buf][khalf][row*32+k]  16 KB
    __shared__ ushort b_s[2][2][64 * 32];   // 16 KB

    const int tid  = threadIdx.x;
    const int lane = tid & 63;
    const int wave = tid >> 6;
    const int wm   = wave >> 1, wn = wave & 1;

    const int srow = (wave << 4) + (lane >> 2);
    const int skc  = (lane & 3) * 8;
    const ushort* aptr = A  + (size_t)(m0 + srow) * KD + skc;
    const ushort* bptr = Bm + (size_t)(n0 + srow) * KD + skc;
    const int ldst = wave * 512;            // ushort offset = 1024 B per wave

    const int r16 = lane & 15;
    const int kc  = lane >> 4;

    f32x4 acc[2][2] = {};

    auto STAGE = [&](int buf, int k0) {
        GLOAD16(aptr + k0,      &a_s[buf][0][ldst]);
        GLOAD16(aptr + k0 + 32, &a_s[buf][1][ldst]);
        GLOAD16(bptr + k0,      &b_s[buf][0][ldst]);
        GLOAD16(bptr + k0 + 32, &b_s[buf][1][ldst]);
    };
    auto COMPUTE = [&](int buf) {
        #pragma unroll
        for (int ks = 0; ks < 2; ++ks) {
            const short8v af0 = *reinterpret_cast<const short8v*>(&a_s[buf][ks][(wm*32 +      r16)*32 + kc*8]);
            const short8v af1 = *reinterpret_cast<const short8v*>(&a_s[buf][ks][(wm*32 + 16 + r16)*32 + kc*8]);
            const short8v bf0 = *reinterpret_cast<const short8v*>(&b_s[buf][ks][(wn*32 +      r16)*32 + kc*8]);
            const short8v bf1 = *reinterpret_cast<const short8v*>(&b_s[buf][ks][(wn*32 + 16 + r16)*32 + kc*8]);
            acc[0][0] = __builtin_amdgcn_mfma_f32_16x16x32_bf16(af0, bf0, acc[0][0], 0, 0, 0);
            acc[0][1] = __builtin_amdgcn_mfma_f32_16x16x32_bf16(af0, bf1, acc[0][1], 0, 0, 0);
            acc[1][0] = __builtin_amdgcn_mfma_f32_16x16x32_bf16(af1, bf0, acc[1][0], 0, 0, 0);
            acc[1][1] = __builtin_amdgcn_mfma_f32_16x16x32_bf16(af1, bf1, acc[1][1], 0, 0, 0);
        }
    };

    STAGE(0, 0);
    __syncthreads();                        // drains vmcnt -> tile 0 resident
    #pragma unroll
    for (int t = 0; t < 7; ++t) {
        const int cur = t & 1;
        STAGE(cur ^ 1, (t + 1) * 64);       // prefetch next tile under MFMA
        COMPUTE(cur);
        __syncthreads();                    // drain: next tile resident
    }
    COMPUTE(1);

    const int rb = (lane >> 4) * 4;
    #pragma unroll
    for (int m = 0; m < 2; ++m) {
        const int grow0 = m0 + wm * 32 + m * 16 + rb;
        #pragma unroll
        for (int n = 0; n < 2; ++n) {
            const int gcol = n0 + wn * 32 + n * 16 + r16;
            const float bv = bias ? bias[gcol] : 0.0f;
            #pragma unroll
            for (int r = 0; r < 4; ++r) {
                const float v = acc[m][n][r] + bv;
                if constexpr (OUT_BF16)
                    ((ushort*)C)[(size_t)(grow0 + r) * NP + gcol] = f2bf(v);
                else
                    ((float*)C)[(size_t)(grow0 + r) * NP + gcol] = v;
            }
        }
    }
}

// Wc_enc = WoB @ WeT^T (z=0), Wc_dec = WoB @ WdT^T (z=1); 512x512 bf16 out
__global__ __launch_bounds__(256) void wc_gemm(
    const ushort* __restrict__ WoB, const ushort* __restrict__ WeT,
    const ushort* __restrict__ WdT, ushort* __restrict__ WcE,
    ushort* __restrict__ WcD)
{
    const bool z = blockIdx.z != 0;
    gemm_body<true>(WoB, z ? WdT : WeT, nullptr, z ? WcD : WcE,
                    blockIdx.y * 64, blockIdx.x * 64);
}

// z=0: EV = encB @ WcE^T + be (4800x512) ; z=1: DV = decB @ WcD^T + bd (512x512)
__global__ __launch_bounds__(256) void evdv_gemm(
    const ushort* __restrict__ encB, const ushort* __restrict__ WcE,
    const float* __restrict__ be, float* __restrict__ EV,
    const ushort* __restrict__ decB, const ushort* __restrict__ WcD,
    const float* __restrict__ bd, float* __restrict__ DV)
{
    const bool z = blockIdx.z != 0;
    if (z && blockIdx.y >= 8) return;     // DV has only 512 rows
    gemm_body<false>(z ? decB : encB, z ? WcD : WcE, z ? bd : be,
                     z ? DV : EV, blockIdx.y * 64, blockIdx.x * 64);
}

// ---------------------------------------------------------------------------
// out[b,t,u,v] = EV[bt,v] + DV[b*U+u,v], v<500; EV/DV row stride 512.
// Block = one bt. tx = v4 lane (0..127, 125 active), ty = u parity.
// EV row value in-register; nontemporal via native ext-vector f32x4.
// ---------------------------------------------------------------------------
__global__ __launch_bounds__(256) void bcast_add(
    const float* __restrict__ EV, const float* __restrict__ DV,
    float* __restrict__ out)
{
    __shared__ f32x4 evs[128];
    const int bt = blockIdx.x;
    const int b  = bt / T_;
    const int tx = threadIdx.x & 127;
    const int ty = threadIdx.x >> 7;

    if (threadIdx.x < 125) {
        const f32x4* evrow = reinterpret_cast<const f32x4*>(EV + (size_t)bt * NP);
        evs[threadIdx.x] = __builtin_nontemporal_load(evrow + threadIdx.x);
    }
    __syncthreads();

    const bool active = tx < 125;
    const f32x4 e = active ? evs[tx] : (f32x4){0, 0, 0, 0};
    const float* dvb  = DV + (size_t)b * U_ * NP + tx * 4;
    f32x4*       orow = reinterpret_cast<f32x4*>(out + (size_t)bt * U_ * 500) + tx;

    if (active) {
        #pragma unroll 3
        for (int u = ty; u < U_; u += 2) {
            const f32x4 d = *reinterpret_cast<const f32x4*>(dvb + u * NP);
            __builtin_nontemporal_store(e + d, orow + u * 125);
        }
    }
}

extern "C" void kernel_launch(void* const* d_in, const int* in_sizes, int n_in,
                              void* d_out, int out_size, void* d_ws, size_t ws_size,
                              hipStream_t stream) {
    const float* enc   = (const float*)d_in[0];
    const float* dec   = (const float*)d_in[1];
    const float* W_enc = (const float*)d_in[2];
    const float* b_enc = (const float*)d_in[3];
    const float* W_dec = (const float*)d_in[4];
    const float* b_dec = (const float*)d_in[5];
    const float* W_out = (const float*)d_in[6];
    const float* b_out = (const float*)d_in[7];
    float* out = (float*)d_out;

    // Workspace layout (16B aligned): ~19 MB
    char* p = (char*)d_ws;
    ushort* encB = (ushort*)p;            p += (size_t)BT_ * 512 * 2;   // 4.92 MB
    ushort* decB = (ushort*)p;            p += (size_t)512 * 512 * 2;
    ushort* WeT  = (ushort*)p;            p += (size_t)512 * 512 * 2;
    ushort* WdT  = (ushort*)p;            p += (size_t)512 * 512 * 2;
    ushort* WoB  = (ushort*)p;            p += (size_t)512 * 512 * 2;
    ushort* WcE  = (ushort*)p;            p += (size_t)512 * 512 * 2;
    ushort* WcD  = (ushort*)p;            p += (size_t)512 * 512 * 2;
    float*  be   = (float*)p;             p += 512 * 4;
    float*  bd   = (float*)p;             p += 512 * 4;
    float*  EV   = (float*)p;             p += (size_t)BT_ * 512 * 4;   // 9.83 MB
    float*  DV   = (float*)p;

    dim3 blk(256);

    prep<<<dim3(1584), blk, 0, stream>>>(
        enc, dec, W_enc, W_dec, W_out, b_enc, b_dec, b_out,
        encB, decB, WeT, WdT, WoB, be, bd);

    wc_gemm<<<dim3(8, 8, 2), blk, 0, stream>>>(WoB, WeT, WdT, WcE, WcD);

    evdv_gemm<<<dim3(8, BT_ / 64, 2), blk, 0, stream>>>(
        encB, WcE, be, EV, decB, WcD, bd, DV);

    bcast_add<<<dim3(BT_), blk, 0, stream>>>(EV, DV, out);
}

// Round 6
// 92.371 us; speedup vs baseline: 1.1281x; 1.1281x over previous
//
#include <hip/hip_runtime.h>

// Problem sizes (compile-time)
constexpr int B_ = 16, T_ = 300, U_ = 30;
constexpr int J_ = 512;       // ENC/DEC/JOINER dim
constexpr int V_ = 500;       // VOCAB
constexpr int BT_ = B_ * T_;  // 4800 (divisible by 64)
constexpr int BU_ = B_ * U_;  // 480
constexpr int KD  = 512;      // K of all GEMMs
constexpr int NP  = 512;      // padded N / row stride

typedef __attribute__((ext_vector_type(8))) short short8v;  // 8 bf16
typedef __attribute__((ext_vector_type(4))) float f32x4;    // native 16B vector

__device__ __forceinline__ ushort f2bf(float f) {
    unsigned u = __builtin_bit_cast(unsigned, f);
    u += 0x7FFFu + ((u >> 16) & 1u);
    return (ushort)(u >> 16);
}

// direct global->LDS async copy, 16B per lane (wave-uniform LDS base)
#define GLOAD16(gsrc, ldst)                                                   \
    __builtin_amdgcn_global_load_lds(                                         \
        (const __attribute__((address_space(1))) unsigned int*)(const void*)(gsrc), \
        (__attribute__((address_space(3))) unsigned int*)(void*)(ldst), 16, 0, 0)

// ---------------------------------------------------------------------------
// prep: one launch, role by blockIdx.x range (unchanged from round 3)
// ---------------------------------------------------------------------------
__global__ __launch_bounds__(256) void prep(
    const float* __restrict__ enc, const float* __restrict__ dec,
    const float* __restrict__ W_enc, const float* __restrict__ W_dec,
    const float* __restrict__ W_out, const float* __restrict__ b_enc,
    const float* __restrict__ b_dec, const float* __restrict__ b_out,
    ushort* __restrict__ encB, ushort* __restrict__ decB,
    ushort* __restrict__ WeT, ushort* __restrict__ WdT,
    ushort* __restrict__ WoB, float* __restrict__ be, float* __restrict__ bd)
{
    __shared__ ushort ts[64][65];
    const int bid = blockIdx.x;
    const int tid = threadIdx.x;

    if (bid < 1200) {                       // enc convert: 2048 floats/block
        const size_t idx = (size_t)bid * 2048 + tid * 8;
        float4 f0 = *reinterpret_cast<const float4*>(enc + idx);
        float4 f1 = *reinterpret_cast<const float4*>(enc + idx + 4);
        short8v o; o[0]=(short)f2bf(f0.x); o[1]=(short)f2bf(f0.y);
        o[2]=(short)f2bf(f0.z); o[3]=(short)f2bf(f0.w);
        o[4]=(short)f2bf(f1.x); o[5]=(short)f2bf(f1.y);
        o[6]=(short)f2bf(f1.z); o[7]=(short)f2bf(f1.w);
        *reinterpret_cast<short8v*>(encB + idx) = o;
    } else if (bid < 1328) {                // dec convert + pad
        const size_t idx = (size_t)(bid - 1200) * 2048 + tid * 8;
        const int row = (int)(idx >> 9);
        short8v o = {};
        if (row < BU_) {
            float4 f0 = *reinterpret_cast<const float4*>(dec + idx);
            float4 f1 = *reinterpret_cast<const float4*>(dec + idx + 4);
            o[0]=(short)f2bf(f0.x); o[1]=(short)f2bf(f0.y);
            o[2]=(short)f2bf(f0.z); o[3]=(short)f2bf(f0.w);
            o[4]=(short)f2bf(f1.x); o[5]=(short)f2bf(f1.y);
            o[6]=(short)f2bf(f1.z); o[7]=(short)f2bf(f1.w);
        }
        *reinterpret_cast<short8v*>(decB + idx) = o;
    } else if (bid < 1456) {                // transpose W_enc / W_dec (64x64 tiles)
        const bool isE = bid < 1392;
        const int t = bid - (isE ? 1328 : 1392);   // 0..63
        const float*  W = isE ? W_enc : W_dec;
        ushort*      WT = isE ? WeT : WdT;
        const int r0 = (t >> 3) * 64, c0 = (t & 7) * 64;
        #pragma unroll
        for (int it = 0; it < 4; ++it) {
            const int idx = tid + it * 256;        // 0..1023
            const int r = idx >> 4, c4 = (idx & 15) * 4;
            float4 f = *reinterpret_cast<const float4*>(&W[(size_t)(r0 + r) * 512 + c0 + c4]);
            ts[r][c4 + 0] = f2bf(f.x); ts[r][c4 + 1] = f2bf(f.y);
            ts[r][c4 + 2] = f2bf(f.z); ts[r][c4 + 3] = f2bf(f.w);
        }
        __syncthreads();
        #pragma unroll
        for (int it = 0; it < 4; ++it) {
            const int idx = tid + it * 256;
            const int c = idx >> 4, r4 = (idx & 15) * 4;
            ushort4 o;
            o.x = ts[r4 + 0][c]; o.y = ts[r4 + 1][c];
            o.z = ts[r4 + 2][c]; o.w = ts[r4 + 3][c];
            *reinterpret_cast<ushort4*>(&WT[(size_t)(c0 + c) * 512 + r0 + r4]) = o;
        }
    } else {                                // W_out rows + folded biases
        const int v    = (bid - 1456) * 4 + (tid >> 6);  // 0..511
        const int lane = tid & 63;
        float4 f0 = make_float4(0, 0, 0, 0), f1 = f0;
        if (v < V_) {
            f0 = *reinterpret_cast<const float4*>(&W_out[(size_t)v * 512 + lane * 8]);
            f1 = *reinterpret_cast<const float4*>(&W_out[(size_t)v * 512 + lane * 8 + 4]);
        }
        short8v o; o[0]=(short)f2bf(f0.x); o[1]=(short)f2bf(f0.y);
        o[2]=(short)f2bf(f0.z); o[3]=(short)f2bf(f0.w);
        o[4]=(short)f2bf(f1.x); o[5]=(short)f2bf(f1.y);
        o[6]=(short)f2bf(f1.z); o[7]=(short)f2bf(f1.w);
        *reinterpret_cast<short8v*>(WoB + (size_t)v * 512 + lane * 8) = o;

        float4 e0 = *reinterpret_cast<const float4*>(b_enc + lane * 8);
        float4 e1 = *reinterpret_cast<const float4*>(b_enc + lane * 8 + 4);
        float4 d0 = *reinterpret_cast<const float4*>(b_dec + lane * 8);
        float4 d1 = *reinterpret_cast<const float4*>(b_dec + lane * 8 + 4);
        float sE = f0.x*e0.x + f0.y*e0.y + f0.z*e0.z + f0.w*e0.w
                 + f1.x*e1.x + f1.y*e1.y + f1.z*e1.z + f1.w*e1.w;
        float sD = f0.x*d0.x + f0.y*d0.y + f0.z*d0.z + f0.w*d0.w
                 + f1.x*d1.x + f1.y*d1.y + f1.z*d1.z + f1.w*d1.w;
        #pragma unroll
        for (int off = 32; off > 0; off >>= 1) {
            sE += __shfl_down(sE, off);
            sD += __shfl_down(sD, off);
        }
        if (lane == 0) {
            be[v] = (v < V_) ? sE : 0.0f;
            bd[v] = (v < V_) ? (sD + b_out[v]) : 0.0f;
        }
    }
}

// ---------------------------------------------------------------------------
// bf16 NT GEMM body — round-3 exact (single-buffer BK=32, known-good 83.6us).
// C(M x 512) = A(M x 512) @ B(512 x 512)^T [+ bias]
// ---------------------------------------------------------------------------
template <bool OUT_BF16>
__device__ __forceinline__ void gemm_body(
    const ushort* __restrict__ A, const ushort* __restrict__ Bm,
    const float* __restrict__ bias, void* __restrict__ C,
    int m0, int n0)
{
    __shared__ ushort a_s[64 * 32];
    __shared__ ushort b_s[64 * 32];

    const int tid  = threadIdx.x;
    const int lane = tid & 63;
    const int wave = tid >> 6;
    const int wm   = wave >> 1, wn = wave & 1;

    const int srow = (wave << 4) + (lane >> 2);
    const int skc  = (lane & 3) * 8;
    ushort* a_dst = a_s + wave * 512;
    ushort* b_dst = b_s + wave * 512;

    const int r16 = lane & 15;
    const int kc  = lane >> 4;

    f32x4 acc[2][2] = {};

    for (int k0 = 0; k0 < KD; k0 += 32) {
        GLOAD16(A  + (size_t)(m0 + srow) * KD + k0 + skc, a_dst);
        GLOAD16(Bm + (size_t)(n0 + srow) * KD + k0 + skc, b_dst);
        __syncthreads();

        const short8v af0 = *reinterpret_cast<const short8v*>(&a_s[(wm*32 +      r16) * 32 + kc*8]);
        const short8v af1 = *reinterpret_cast<const short8v*>(&a_s[(wm*32 + 16 + r16) * 32 + kc*8]);
        const short8v bf0 = *reinterpret_cast<const short8v*>(&b_s[(wn*32 +      r16) * 32 + kc*8]);
        const short8v bf1 = *reinterpret_cast<const short8v*>(&b_s[(wn*32 + 16 + r16) * 32 + kc*8]);

        acc[0][0] = __builtin_amdgcn_mfma_f32_16x16x32_bf16(af0, bf0, acc[0][0], 0, 0, 0);
        acc[0][1] = __builtin_amdgcn_mfma_f32_16x16x32_bf16(af0, bf1, acc[0][1], 0, 0, 0);
        acc[1][0] = __builtin_amdgcn_mfma_f32_16x16x32_bf16(af1, bf0, acc[1][0], 0, 0, 0);
        acc[1][1] = __builtin_amdgcn_mfma_f32_16x16x32_bf16(af1, bf1, acc[1][1], 0, 0, 0);
        __syncthreads();
    }

    const int rb = (lane >> 4) * 4;
    #pragma unroll
    for (int m = 0; m < 2; ++m) {
        const int grow0 = m0 + wm * 32 + m * 16 + rb;
        #pragma unroll
        for (int n = 0; n < 2; ++n) {
            const int gcol = n0 + wn * 32 + n * 16 + r16;
            const float bv = bias ? bias[gcol] : 0.0f;
            #pragma unroll
            for (int r = 0; r < 4; ++r) {
                const float v = acc[m][n][r] + bv;
                if constexpr (OUT_BF16)
                    ((ushort*)C)[(size_t)(grow0 + r) * NP + gcol] = f2bf(v);
                else
                    ((float*)C)[(size_t)(grow0 + r) * NP + gcol] = v;
            }
        }
    }
}

// Wc_enc = WoB @ WeT^T (z=0), Wc_dec = WoB @ WdT^T (z=1); 512x512 bf16 out
__global__ __launch_bounds__(256) void wc_gemm(
    const ushort* __restrict__ WoB, const ushort* __restrict__ WeT,
    const ushort* __restrict__ WdT, ushort* __restrict__ WcE,
    ushort* __restrict__ WcD)
{
    const bool z = blockIdx.z != 0;
    gemm_body<true>(WoB, z ? WdT : WeT, nullptr, z ? WcD : WcE,
                    blockIdx.y * 64, blockIdx.x * 64);
}

// DV = decB @ WcD^T + bd   (512x512, rows >=480 garbage-but-unread)
__global__ __launch_bounds__(256) void dv_gemm(
    const ushort* __restrict__ decB, const ushort* __restrict__ WcD,
    const float* __restrict__ bd, float* __restrict__ DV)
{
    gemm_body<false>(decB, WcD, bd, DV, blockIdx.y * 64, blockIdx.x * 64);
}

// ---------------------------------------------------------------------------
// Fused: EV-tile GEMM (64 bt-rows x 64 v-cols) + broadcast-add + out stream.
//   out[bt, u, vt0+c] = (encB[bt,:]@WcE[vt0+c,:] + be[vt0+c]) + DV[b*30+u, vt0+c]
// grid = (8 vtiles, 75 mtiles). LDS: gemm 8K + evs 18.4K + dvs 17.3K = 43.7 KB.
// evs/dvs row stride 72 floats -> 2-way LDS banks (free per m136).
// ---------------------------------------------------------------------------
__global__ __launch_bounds__(256) void fused_ev_bcast(
    const ushort* __restrict__ encB, const ushort* __restrict__ WcE,
    const float* __restrict__ be, const float* __restrict__ DV,
    float* __restrict__ out)
{
    __shared__ ushort a_s[64 * 32];
    __shared__ ushort b_s[64 * 32];
    __shared__ float  evs[64 * 72];
    __shared__ float  dvs[2 * 30 * 72];

    const int tid  = threadIdx.x;
    const int lane = tid & 63;
    const int wave = tid >> 6;
    const int wm   = wave >> 1, wn = wave & 1;
    const int m0   = blockIdx.y * 64;   // bt tile base
    const int n0   = blockIdx.x * 64;   // v tile base

    const int srow = (wave << 4) + (lane >> 2);
    const int skc  = (lane & 3) * 8;
    ushort* a_dst = a_s + wave * 512;
    ushort* b_dst = b_s + wave * 512;

    const int r16 = lane & 15;
    const int kc  = lane >> 4;

    f32x4 acc[2][2] = {};

    for (int k0 = 0; k0 < KD; k0 += 32) {
        GLOAD16(encB + (size_t)(m0 + srow) * KD + k0 + skc, a_dst);
        GLOAD16(WcE  + (size_t)(n0 + srow) * KD + k0 + skc, b_dst);
        __syncthreads();

        const short8v af0 = *reinterpret_cast<const short8v*>(&a_s[(wm*32 +      r16) * 32 + kc*8]);
        const short8v af1 = *reinterpret_cast<const short8v*>(&a_s[(wm*32 + 16 + r16) * 32 + kc*8]);
        const short8v bf0 = *reinterpret_cast<const short8v*>(&b_s[(wn*32 +      r16) * 32 + kc*8]);
        const short8v bf1 = *reinterpret_cast<const short8v*>(&b_s[(wn*32 + 16 + r16) * 32 + kc*8]);

        acc[0][0] = __builtin_amdgcn_mfma_f32_16x16x32_bf16(af0, bf0, acc[0][0], 0, 0, 0);
        acc[0][1] = __builtin_amdgcn_mfma_f32_16x16x32_bf16(af0, bf1, acc[0][1], 0, 0, 0);
        acc[1][0] = __builtin_amdgcn_mfma_f32_16x16x32_bf16(af1, bf0, acc[1][0], 0, 0, 0);
        acc[1][1] = __builtin_amdgcn_mfma_f32_16x16x32_bf16(af1, bf1, acc[1][1], 0, 0, 0);
        __syncthreads();
    }

    // ---- EV tile + bias -> LDS ----
    const int rb = (lane >> 4) * 4;
    #pragma unroll
    for (int n = 0; n < 2; ++n) {
        const int col = wn * 32 + n * 16 + r16;
        const float bv = be[n0 + col];
        #pragma unroll
        for (int m = 0; m < 2; ++m) {
            const int row = wm * 32 + m * 16 + rb;
            #pragma unroll
            for (int r = 0; r < 4; ++r)
                evs[(row + r) * 72 + col] = acc[m][n][r] + bv;
        }
    }

    // ---- DV slices (b0 and b1; equal when tile doesn't straddle) -> LDS ----
    const int b0 = m0 / T_;
    const int b1 = (m0 + 63) / T_;
    for (int i = tid; i < 960; i += 256) {       // 2 * 30 * 16 f32x4
        const int s   = i / 480;
        const int rem = i - s * 480;
        const int u   = rem >> 4;
        const int v4  = rem & 15;
        const int bb  = s ? b1 : b0;
        const f32x4 d = *reinterpret_cast<const f32x4*>(
            DV + ((size_t)bb * U_ + u) * NP + n0 + 4 * v4);
        *reinterpret_cast<f32x4*>(&dvs[(s * U_ + u) * 72 + 4 * v4]) = d;
    }
    __syncthreads();

    // ---- stream 64 rows x 30 u x 16 f32x4 (13 valid in last vtile) ----
    const int v4  = tid & 15;
    const int nv4 = (n0 == 448) ? 13 : 16;
    if (v4 < nv4) {
        const int rsplit = (b0 + 1) * T_ - m0;   // rows >= rsplit belong to b1
        int u = tid >> 4;                        // 0..15
        int row = 0;
        #pragma unroll 4
        for (int it = 0; it < 120; ++it) {
            const f32x4 e = *reinterpret_cast<const f32x4*>(&evs[row * 72 + 4 * v4]);
            const int bsel = (row >= rsplit) ? 1 : 0;
            const f32x4 d = *reinterpret_cast<const f32x4*>(&dvs[(bsel * U_ + u) * 72 + 4 * v4]);
            float* o = out + ((size_t)(m0 + row) * U_ + u) * V_ + n0 + 4 * v4;
            *reinterpret_cast<f32x4*>(o) = e + d;
            u += 16;
            if (u >= U_) { u -= U_; ++row; }
        }
    }
}

extern "C" void kernel_launch(void* const* d_in, const int* in_sizes, int n_in,
                              void* d_out, int out_size, void* d_ws, size_t ws_size,
                              hipStream_t stream) {
    const float* enc   = (const float*)d_in[0];
    const float* dec   = (const float*)d_in[1];
    const float* W_enc = (const float*)d_in[2];
    const float* b_enc = (const float*)d_in[3];
    const float* W_dec = (const float*)d_in[4];
    const float* b_dec = (const float*)d_in[5];
    const float* W_out = (const float*)d_in[6];
    const float* b_out = (const float*)d_in[7];
    float* out = (float*)d_out;

    // Workspace layout (16B aligned)
    char* p = (char*)d_ws;
    ushort* encB = (ushort*)p;            p += (size_t)BT_ * 512 * 2;   // 4.92 MB
    ushort* decB = (ushort*)p;            p += (size_t)512 * 512 * 2;
    ushort* WeT  = (ushort*)p;            p += (size_t)512 * 512 * 2;
    ushort* WdT  = (ushort*)p;            p += (size_t)512 * 512 * 2;
    ushort* WoB  = (ushort*)p;            p += (size_t)512 * 512 * 2;
    ushort* WcE  = (ushort*)p;            p += (size_t)512 * 512 * 2;
    ushort* WcD  = (ushort*)p;            p += (size_t)512 * 512 * 2;
    float*  be   = (float*)p;             p += 512 * 4;
    float*  bd   = (float*)p;             p += 512 * 4;
    float*  DV   = (float*)p;                                           // 512x512 f32

    dim3 blk(256);

    prep<<<dim3(1584), blk, 0, stream>>>(
        enc, dec, W_enc, W_dec, W_out, b_enc, b_dec, b_out,
        encB, decB, WeT, WdT, WoB, be, bd);

    wc_gemm<<<dim3(8, 8, 2), blk, 0, stream>>>(WoB, WeT, WdT, WcE, WcD);

    dv_gemm<<<dim3(8, 8), blk, 0, stream>>>(decB, WcD, bd, DV);

    fused_ev_bcast<<<dim3(8, BT_ / 64), blk, 0, stream>>>(
        encB, WcE, be, DV, out);
}